// Round 1
// baseline (590.032 us; speedup 1.0000x reference)
//
#include <hip/hip_runtime.h>
#include <hip/hip_bf16.h>

#define C_DIM 128
#define EPS_LN 1e-5f

typedef short bf16x8 __attribute__((ext_vector_type(8)));
typedef float f32x4  __attribute__((ext_vector_type(4)));
typedef __hip_bfloat16 bf16;

__device__ inline unsigned short f2bu(float f) {
    bf16 h = __float2bfloat16(f);
    return *reinterpret_cast<unsigned short*>(&h);
}
__device__ inline float blo(unsigned int u) { return __uint_as_float(u << 16); }
__device__ inline float bhi(unsigned int u) { return __uint_as_float(u & 0xffff0000u); }
__device__ inline ushort4 pack4(float a, float b, float c, float d) {
    ushort4 r; r.x = f2bu(a); r.y = f2bu(b); r.z = f2bu(c); r.w = f2bu(d); return r;
}

// ---------------- weights convert+transpose + bias pack, ONE dispatch ------
// dst (bf16): Wqt|Wkt|Wvt|Wot (4x 128*128) | Wt1[512][128] | Wt2[128][512]
// then packed fp32 bqkv[384] right after.
__global__ __launch_bounds__(256) void wconv_all(
    const float* __restrict__ Wq, const float* __restrict__ Wk,
    const float* __restrict__ Wv, const float* __restrict__ Wo,
    const float* __restrict__ W1, const float* __restrict__ W2,
    const float* __restrict__ bq, const float* __restrict__ bk,
    const float* __restrict__ bv, bf16* __restrict__ dst) {
    int idx = blockIdx.x * 256 + threadIdx.x;
    if (idx < 65536) {                       // four 128x128 weights
        int r = idx >> 14, o = idx & 16383;
        int k = o >> 7, nn = o & 127;
        const float* W = (r == 0) ? Wq : (r == 1) ? Wk : (r == 2) ? Wv : Wo;
        dst[(r << 14) + nn * 128 + k] = __float2bfloat16(W[o]);
    } else if (idx < 131072) {               // W1 [128,512] -> Wt1[n][k]
        int o = idx - 65536;
        int k = o >> 9, nn = o & 511;
        dst[65536 + nn * 128 + k] = __float2bfloat16(W1[o]);
    } else if (idx < 196608) {               // W2 [512,128] -> Wt2[n][k]
        int o = idx - 131072;
        int k = o >> 7, nn = o & 127;
        dst[131072 + nn * 512 + k] = __float2bfloat16(W2[o]);
    } else if (idx < 196992) {               // packed bqkv[384] fp32
        int j = idx - 196608;
        int grp = j >> 7, col = j & 127;
        const float* bp = (grp == 0) ? bq : (grp == 1) ? bk : bv;
        ((float*)(dst + 196608))[j] = bp[col];
    }
}

__global__ __launch_bounds__(256) void zeroi_kernel(int* __restrict__ p, int n) {
    int i = blockIdx.x * 256 + threadIdx.x;
    if (i < n) p[i] = 0;
}

// ---------------- LayerNorm fp32 -> bf16, one wave per row -----------------
__global__ __launch_bounds__(256) void ln_kernel(
    const float* __restrict__ x, const float* __restrict__ g,
    const float* __restrict__ b, bf16* __restrict__ out, int n) {
    int wave = threadIdx.x >> 6;
    int lane = threadIdx.x & 63;
    int row = blockIdx.x * 4 + wave;
    if (row >= n) return;
    float2 v = ((const float2*)(x + (size_t)row * C_DIM))[lane];
    float s  = v.x + v.y;
    float ss = v.x * v.x + v.y * v.y;
    #pragma unroll
    for (int o = 1; o < 64; o <<= 1) {
        s  += __shfl_xor(s, o);
        ss += __shfl_xor(ss, o);
    }
    float mu  = s * (1.0f / C_DIM);
    float var = ss * (1.0f / C_DIM) - mu * mu;
    float rs  = rsqrtf(var + EPS_LN);
    float2 gg = ((const float2*)g)[lane];
    float2 bb = ((const float2*)b)[lane];
    __hip_bfloat162 o2;
    o2.x = __float2bfloat16((v.x - mu) * rs * gg.x + bb.x);
    o2.y = __float2bfloat16((v.y - mu) * rs * gg.y + bb.y);
    ((__hip_bfloat162*)(out + (size_t)row * C_DIM))[lane] = o2;
}

// ---------------- LDS-staged MFMA GEMM -------------------------------------
// Block: 128 rows x 128 cols of C; 4 waves, each 32 rows x 128 cols.
// A [M,lda] bf16 row-major; Bt [Ncols][Kfull] bf16 (row = output col).
// Output col-block = blockIdx.y: Bt rows colBlk*128.., bias biasBase+colBlk*128,
// C pointer = Cd + colBlk*obStride (elements).
// Operand-swapped mfma(bf, af, acc): lane(m,q) reg r = C[row0+..+m][ct*16+q*4+r].
template<bool OUTBF16, bool RELU, bool FUSE_LN, int KSTEPS>
__global__ __launch_bounds__(256) void gemm_lds(
    const bf16* __restrict__ A, int lda,
    const bf16* __restrict__ Bt, int Kfull,
    const float* __restrict__ biasBase,
    void* __restrict__ Cd, int ldc, size_t obStride,
    const float* __restrict__ resid, int ldres,
    int M,
    const float* __restrict__ g, const float* __restrict__ be,
    bf16* __restrict__ h2) {
    __shared__ bf16 As[128][136];   // +8 pad: frag reads 2-way (free)
    __shared__ bf16 Bs[128][136];
    int tid  = threadIdx.x;
    int lane = tid & 63;
    int w    = tid >> 6;
    int m = lane & 15, q = lane >> 4;
    int row0 = blockIdx.x * 128;
    const bf16* Bbase = Bt + (size_t)blockIdx.y * 128 * Kfull;

    f32x4 acc[2][8];
    #pragma unroll
    for (int rt = 0; rt < 2; rt++)
        #pragma unroll
        for (int ct = 0; ct < 8; ct++) acc[rt][ct] = (f32x4){0.f, 0.f, 0.f, 0.f};

    int sr = tid >> 1, sch = tid & 1;        // staging: row, 128B-half
    int gr = row0 + sr;

    for (int kt = 0; kt < KSTEPS; kt++) {
        // stage A tile [128][128]
        {
            const uint4* gp = (const uint4*)(A + (size_t)gr * lda + kt * 128 + sch * 64);
            uint4* sp = (uint4*)&As[sr][sch * 64];
            if (gr < M) {
                #pragma unroll
                for (int i = 0; i < 8; i++) sp[i] = gp[i];
            } else {
                uint4 z = make_uint4(0, 0, 0, 0);
                #pragma unroll
                for (int i = 0; i < 8; i++) sp[i] = z;
            }
        }
        // stage B tile [128][128] (Ncols always multiple of 128)
        {
            const uint4* gp = (const uint4*)(Bbase + (size_t)sr * Kfull + kt * 128 + sch * 64);
            uint4* sp = (uint4*)&Bs[sr][sch * 64];
            #pragma unroll
            for (int i = 0; i < 8; i++) sp[i] = gp[i];
        }
        __syncthreads();
        #pragma unroll
        for (int ks = 0; ks < 4; ks++) {
            bf16x8 af0 = *(const bf16x8*)&As[w * 32 + m][ks * 32 + q * 8];
            bf16x8 af1 = *(const bf16x8*)&As[w * 32 + 16 + m][ks * 32 + q * 8];
            #pragma unroll
            for (int ct = 0; ct < 8; ct++) {
                bf16x8 bf = *(const bf16x8*)&Bs[ct * 16 + m][ks * 32 + q * 8];
                acc[0][ct] = __builtin_amdgcn_mfma_f32_16x16x32_bf16(bf, af0, acc[0][ct], 0, 0, 0);
                acc[1][ct] = __builtin_amdgcn_mfma_f32_16x16x32_bf16(bf, af1, acc[1][ct], 0, 0, 0);
            }
        }
        if (kt + 1 < KSTEPS) __syncthreads();
    }

    // ---- epilogue ----
    #pragma unroll
    for (int rt = 0; rt < 2; rt++) {
        int row = row0 + w * 32 + rt * 16 + m;
        bool valid = row < M;
        float vals[8][4];
        #pragma unroll
        for (int ct = 0; ct < 8; ct++) {
            int col = ct * 16 + q * 4;
            float4 bv = make_float4(0.f, 0.f, 0.f, 0.f);
            if (biasBase) bv = *(const float4*)(biasBase + blockIdx.y * 128 + col);
            float4 rv = make_float4(0.f, 0.f, 0.f, 0.f);
            if (resid && valid) rv = *(const float4*)(resid + (size_t)row * ldres + col);
            vals[ct][0] = acc[rt][ct][0] + bv.x + rv.x;
            vals[ct][1] = acc[rt][ct][1] + bv.y + rv.y;
            vals[ct][2] = acc[rt][ct][2] + bv.z + rv.z;
            vals[ct][3] = acc[rt][ct][3] + bv.w + rv.w;
        }
        if (FUSE_LN) {
            // row spans lanes {m, m+16, m+32, m+48}: reduce over q via xor 16,32
            float s1 = 0.f, s2 = 0.f;
            #pragma unroll
            for (int ct = 0; ct < 8; ct++)
                #pragma unroll
                for (int r = 0; r < 4; r++) { s1 += vals[ct][r]; s2 += vals[ct][r] * vals[ct][r]; }
            s1 += __shfl_xor(s1, 16); s1 += __shfl_xor(s1, 32);
            s2 += __shfl_xor(s2, 16); s2 += __shfl_xor(s2, 32);
            float mu  = s1 * (1.0f / 128.f);
            float var = s2 * (1.0f / 128.f) - mu * mu;
            float rs  = rsqrtf(var + EPS_LN);
            if (valid) {
                #pragma unroll
                for (int ct = 0; ct < 8; ct++) {
                    int col = ct * 16 + q * 4;
                    *(float4*)((float*)Cd + (size_t)row * ldc + col) =
                        make_float4(vals[ct][0], vals[ct][1], vals[ct][2], vals[ct][3]);
                    float4 gg = *(const float4*)(g + col);
                    float4 bb = *(const float4*)(be + col);
                    *(ushort4*)(h2 + (size_t)row * 128 + col) =
                        pack4((vals[ct][0] - mu) * rs * gg.x + bb.x,
                              (vals[ct][1] - mu) * rs * gg.y + bb.y,
                              (vals[ct][2] - mu) * rs * gg.z + bb.z,
                              (vals[ct][3] - mu) * rs * gg.w + bb.w);
                }
            }
        } else if (valid) {
            #pragma unroll
            for (int ct = 0; ct < 8; ct++) {
                int col = ct * 16 + q * 4;
                float v0 = vals[ct][0], v1 = vals[ct][1];
                float v2 = vals[ct][2], v3 = vals[ct][3];
                if (RELU) {
                    v0 = fmaxf(v0, 0.f); v1 = fmaxf(v1, 0.f);
                    v2 = fmaxf(v2, 0.f); v3 = fmaxf(v3, 0.f);
                }
                if (OUTBF16) {
                    *(ushort4*)((bf16*)Cd + blockIdx.y * obStride + (size_t)row * ldc + col) =
                        pack4(v0, v1, v2, v3);
                } else {
                    *(float4*)((float*)Cd + blockIdx.y * obStride + (size_t)row * ldc + col) =
                        make_float4(v0, v1, v2, v3);
                }
            }
        }
    }
}

// ---------------- fused FFN: relu(h2@W1+b1)@W2 + b2 + resid -> out ---------
// One block = 128 rows. Stage h2 tile once; loop 4 chunks of the 512-wide
// intermediate: GEMM1 into regs, ReLU+bias -> u chunk bf16 in LDS (reusing
// Bs), GEMM2 partial-accumulate with W2 fragments direct from global (W2t is
// 128 KB, L2-resident). Eliminates the 205 MB u[N,512] HBM round-trip.
__global__ __launch_bounds__(256) void ffn_fused(
    const bf16* __restrict__ Ain,   // h2 [M,128] bf16
    const bf16* __restrict__ W1t,   // [512][128] bf16 (row = interm col)
    const bf16* __restrict__ W2t,   // [128][512] bf16 (row = out col)
    const float* __restrict__ b1,   // [512]
    const float* __restrict__ b2,   // [128]
    const float* __restrict__ resid,// [M,128] fp32 (= out from Wo stage)
    float* __restrict__ outp,       // [M,128] fp32
    int M) {
    __shared__ bf16 As[128][136];
    __shared__ bf16 Bs[128][136];   // W1 chunk, then u chunk (bf16)
    int tid  = threadIdx.x;
    int lane = tid & 63;
    int w    = tid >> 6;
    int m = lane & 15, q = lane >> 4;
    int row0 = blockIdx.x * 128;
    int sr = tid >> 1, sch = tid & 1;
    int gr = row0 + sr;

    f32x4 accO[2][8];
    #pragma unroll
    for (int rt = 0; rt < 2; rt++)
        #pragma unroll
        for (int ct = 0; ct < 8; ct++) accO[rt][ct] = (f32x4){0.f, 0.f, 0.f, 0.f};

    // stage A (h2 tile) once
    {
        const uint4* gp = (const uint4*)(Ain + (size_t)gr * 128 + sch * 64);
        uint4* sp = (uint4*)&As[sr][sch * 64];
        if (gr < M) {
            #pragma unroll
            for (int i = 0; i < 8; i++) sp[i] = gp[i];
        } else {
            uint4 z = make_uint4(0, 0, 0, 0);
            #pragma unroll
            for (int i = 0; i < 8; i++) sp[i] = z;
        }
    }

    for (int c = 0; c < 4; c++) {
        // stage W1 chunk rows c*128 .. c*128+127 into Bs
        {
            const uint4* gp = (const uint4*)(W1t + (size_t)(c * 128 + sr) * 128 + sch * 64);
            uint4* sp = (uint4*)&Bs[sr][sch * 64];
            #pragma unroll
            for (int i = 0; i < 8; i++) sp[i] = gp[i];
        }
        __syncthreads();

        // GEMM1: acc1 = h2_tile @ W1_chunk  (u rows = out rows, u cols = chunk)
        f32x4 acc1[2][8];
        #pragma unroll
        for (int rt = 0; rt < 2; rt++)
            #pragma unroll
            for (int ct = 0; ct < 8; ct++) acc1[rt][ct] = (f32x4){0.f, 0.f, 0.f, 0.f};
        #pragma unroll
        for (int ks = 0; ks < 4; ks++) {
            bf16x8 af0 = *(const bf16x8*)&As[w * 32 + m][ks * 32 + q * 8];
            bf16x8 af1 = *(const bf16x8*)&As[w * 32 + 16 + m][ks * 32 + q * 8];
            #pragma unroll
            for (int ct = 0; ct < 8; ct++) {
                bf16x8 bfB = *(const bf16x8*)&Bs[ct * 16 + m][ks * 32 + q * 8];
                acc1[0][ct] = __builtin_amdgcn_mfma_f32_16x16x32_bf16(bfB, af0, acc1[0][ct], 0, 0, 0);
                acc1[1][ct] = __builtin_amdgcn_mfma_f32_16x16x32_bf16(bfB, af1, acc1[1][ct], 0, 0, 0);
            }
        }
        __syncthreads();   // all waves done reading Bs (W1 chunk)

        // ReLU + b1, write u chunk (bf16, same rounding as unfused path) -> Bs
        #pragma unroll
        for (int rt = 0; rt < 2; rt++) {
            int urow = w * 32 + rt * 16 + m;
            #pragma unroll
            for (int ct = 0; ct < 8; ct++) {
                int col = ct * 16 + q * 4;
                float4 bv = *(const float4*)(b1 + c * 128 + col);
                *(ushort4*)&Bs[urow][col] = pack4(
                    fmaxf(acc1[rt][ct][0] + bv.x, 0.f),
                    fmaxf(acc1[rt][ct][1] + bv.y, 0.f),
                    fmaxf(acc1[rt][ct][2] + bv.z, 0.f),
                    fmaxf(acc1[rt][ct][3] + bv.w, 0.f));
            }
        }
        __syncthreads();

        // GEMM2 partial: accO += u_chunk @ W2[:, chunk]; W2 frags from global (L2)
        #pragma unroll
        for (int ks = 0; ks < 4; ks++) {
            bf16x8 af0 = *(const bf16x8*)&Bs[w * 32 + m][ks * 32 + q * 8];
            bf16x8 af1 = *(const bf16x8*)&Bs[w * 32 + 16 + m][ks * 32 + q * 8];
            #pragma unroll
            for (int ct = 0; ct < 8; ct++) {
                bf16x8 bfW = *(const bf16x8*)(W2t + (size_t)(ct * 16 + m) * 512
                                              + c * 128 + ks * 32 + q * 8);
                accO[0][ct] = __builtin_amdgcn_mfma_f32_16x16x32_bf16(bfW, af0, accO[0][ct], 0, 0, 0);
                accO[1][ct] = __builtin_amdgcn_mfma_f32_16x16x32_bf16(bfW, af1, accO[1][ct], 0, 0, 0);
            }
        }
        if (c + 1 < 4) __syncthreads();   // before next chunk overwrites Bs
    }

    // epilogue: out = accO + b2 + resid (fp32)
    #pragma unroll
    for (int rt = 0; rt < 2; rt++) {
        int row = row0 + w * 32 + rt * 16 + m;
        if (row >= M) continue;
        #pragma unroll
        for (int ct = 0; ct < 8; ct++) {
            int col = ct * 16 + q * 4;
            float4 bv = *(const float4*)(b2 + col);
            float4 rv = *(const float4*)(resid + (size_t)row * 128 + col);
            *(float4*)(outp + (size_t)row * 128 + col) = make_float4(
                accO[rt][ct][0] + bv.x + rv.x,
                accO[rt][ct][1] + bv.y + rv.y,
                accO[rt][ct][2] + bv.z + rv.z,
                accO[rt][ct][3] + bv.w + rv.w);
        }
    }
}

// ---------------- attention: 8 edges/wave, one head per lane ---------------
__device__ inline float dot8(uint4 a, uint4 b) {
    return blo(a.x) * blo(b.x) + bhi(a.x) * bhi(b.x)
         + blo(a.y) * blo(b.y) + bhi(a.y) * bhi(b.y)
         + blo(a.z) * blo(b.z) + bhi(a.z) * bhi(b.z)
         + blo(a.w) * blo(b.w) + bhi(a.w) * bhi(b.w);
}

__global__ __launch_bounds__(256) void attn_kernel(
    const bf16* __restrict__ Q, const bf16* __restrict__ K,
    const int* __restrict__ eidx, float* __restrict__ attn, int E_) {
    int gw = blockIdx.x * 4 + (threadIdx.x >> 6);
    int lane = threadIdx.x & 63;
    int e = gw * 8 + (lane >> 3);
    int h = lane & 7;
    bool v = e < E_;
    int src = v ? eidx[e] : 0;
    int dst = v ? eidx[E_ + e] : 0;
    const uint4* qp = (const uint4*)(Q + (size_t)dst * 128 + h * 16);
    const uint4* kp = (const uint4*)(K + (size_t)src * 128 + h * 16);
    uint4 q0 = qp[0], q1 = qp[1];
    uint4 k0 = kp[0], k1 = kp[1];
    float s = (dot8(q0, k0) + dot8(q1, k1)) * 0.25f;   // / sqrt(16)
    float mx = s;
    mx = fmaxf(mx, __shfl_xor(mx, 1));
    mx = fmaxf(mx, __shfl_xor(mx, 2));
    mx = fmaxf(mx, __shfl_xor(mx, 4));
    float ex = expf(s - mx);
    float sum = ex;
    sum += __shfl_xor(sum, 1);
    sum += __shfl_xor(sum, 2);
    sum += __shfl_xor(sum, 4);
    if (v) attn[(size_t)e * 8 + h] = ex / sum;   // coalesced: gw*64+lane
}

// ---------------- CSR build ------------------------------------------------
__global__ __launch_bounds__(256) void hist_kernel(
    const int* __restrict__ eidx, int* __restrict__ deg, int E_) {
    int e = blockIdx.x * 256 + threadIdx.x;
    if (e >= E_) return;
    atomicAdd(&deg[eidx[E_ + e]], 1);
}

__global__ __launch_bounds__(256) void alloc_kernel(
    const int* __restrict__ deg, int* __restrict__ start,
    int* __restrict__ cursor, int* __restrict__ counter, int n) {
    int i = blockIdx.x * 256 + threadIdx.x;
    if (i >= n) return;
    int d = deg[i];
    int s = atomicAdd(counter, d);
    start[i] = s;
    cursor[i] = s;
}

__global__ __launch_bounds__(256) void scatter_kernel(
    const int* __restrict__ eidx, int* __restrict__ cursor,
    int2* __restrict__ edata, int E_) {
    int e = blockIdx.x * 256 + threadIdx.x;
    if (e >= E_) return;
    int src = eidx[e];
    int dst = eidx[E_ + e];
    int pos = atomicAdd(&cursor[dst], 1);
    edata[pos] = make_int2(src, e);
}

// ---------------- aggregation: one wave/node, 2-way unrolled ---------------
__global__ __launch_bounds__(256) void aggr_kernel(
    const bf16* __restrict__ V, const float* __restrict__ attnW,
    const int* __restrict__ start, const int* __restrict__ deg,
    const int2* __restrict__ edata, bf16* __restrict__ ag, int n) {
    int wave = threadIdx.x >> 6;
    int lane = threadIdx.x & 63;
    int i = blockIdx.x * 4 + wave;
    if (i >= n) return;
    int s = start[i], d = deg[i];
    int h = lane >> 3;
    float ax = 0.f, ay = 0.f, bx = 0.f, by = 0.f;
    int j = s, e_ = s + d;
    for (; j + 2 <= e_; j += 2) {
        int2 e0 = edata[j], e1 = edata[j + 1];
        float a0 = attnW[(size_t)e0.y * 8 + h];
        float a1 = attnW[(size_t)e1.y * 8 + h];
        unsigned u0 = ((const unsigned*)(V + (size_t)e0.x * 128))[lane];
        unsigned u1 = ((const unsigned*)(V + (size_t)e1.x * 128))[lane];
        ax += a0 * blo(u0); ay += a0 * bhi(u0);
        bx += a1 * blo(u1); by += a1 * bhi(u1);
    }
    if (j < e_) {
        int2 e0 = edata[j];
        float a0 = attnW[(size_t)e0.y * 8 + h];
        unsigned u0 = ((const unsigned*)(V + (size_t)e0.x * 128))[lane];
        ax += a0 * blo(u0); ay += a0 * bhi(u0);
    }
    ax += bx; ay += by;
    __hip_bfloat162 o2;
    o2.x = __float2bfloat16(ax);
    o2.y = __float2bfloat16(ay);
    ((__hip_bfloat162*)(ag + (size_t)i * 128))[lane] = o2;
}

extern "C" void kernel_launch(void* const* d_in, const int* in_sizes, int n_in,
                              void* d_out, int out_size, void* d_ws, size_t ws_size,
                              hipStream_t stream) {
    const float* x   = (const float*)d_in[0];
    const int*  eidx = (const int*)d_in[1];
    const float* Wq = (const float*)d_in[2];  const float* bq = (const float*)d_in[3];
    const float* Wk = (const float*)d_in[4];  const float* bk = (const float*)d_in[5];
    const float* Wv = (const float*)d_in[6];  const float* bv = (const float*)d_in[7];
    const float* Wo = (const float*)d_in[8];  const float* bo = (const float*)d_in[9];
    const float* W1 = (const float*)d_in[10]; const float* b1 = (const float*)d_in[11];
    const float* W2 = (const float*)d_in[12]; const float* b2 = (const float*)d_in[13];
    const float* g1 = (const float*)d_in[14]; const float* be1 = (const float*)d_in[15];
    const float* g2 = (const float*)d_in[16]; const float* be2 = (const float*)d_in[17];
    float* out = (float*)d_out;

    int n  = in_sizes[0] / C_DIM;   // 100000
    int E_ = in_sizes[1] / 2;       // 600000
    size_t nf = (size_t)n * 128;

    // ---- workspace (~154 MB) ----
    bf16* Wt    = (bf16*)d_ws;                // 196608 bf16 transposed weights
    float* bqkv = (float*)(Wt + 196608);      // packed [bq|bk|bv]
    bf16* reg0  = (bf16*)(bqkv + 384);        // 4*nf: h1|Q|K|V
    bf16* h1 = reg0;
    bf16* Qb = reg0 + nf;
    bf16* Kb = reg0 + 2 * nf;
    bf16* Vb = reg0 + 3 * nf;
    bf16* ag = reg0 + 4 * nf;                 // [N,128]
    char* r2 = (char*)(ag + nf);              // union region
    float* attnW = (float*)r2;                // [E,8] fp32
    int2* edata  = (int2*)(attnW + (size_t)E_ * 8);
    int*  ideg   = (int*)(edata + E_);
    int*  counter = ideg + n;
    int*  istart  = ideg + n + 1;
    int*  icursor = istart + n;
    bf16* h2 = (bf16*)r2;                     // overlays attnW/edata/CSR after aggr

    dim3 b256(256);
    dim3 lnGrid((n + 3) / 4);
    int rb = (n + 127) / 128;                 // 782
    dim3 eGrid8((E_ + 31) / 32);
    dim3 eGrid((E_ + 255) / 256);
    dim3 nGrid((n + 255) / 256);
    dim3 n1Grid((n + 1 + 255) / 256);
    dim3 n4Grid((n + 3) / 4);

    // weights -> bf16 transposed + packed bqkv (one dispatch)
    wconv_all<<<dim3(770), b256, 0, stream>>>(Wq, Wk, Wv, Wo, W1, W2, bq, bk, bv, Wt);
    // zero deg+counter
    zeroi_kernel<<<n1Grid, b256, 0, stream>>>(ideg, n + 1);
    // LN1: x -> h1
    ln_kernel<<<lnGrid, b256, 0, stream>>>(x, g1, be1, h1, n);
    // QKV: one dispatch, col-blocks -> Q|K|V buffers (obStride = nf)
    gemm_lds<true, false, false, 1><<<dim3(rb, 3), b256, 0, stream>>>(
        h1, 128, Wt, 128, bqkv, Qb, 128, nf, nullptr, 0, n, nullptr, nullptr, nullptr);
    // attention weights
    attn_kernel<<<eGrid8, b256, 0, stream>>>(Qb, Kb, eidx, attnW, E_);
    // CSR build
    hist_kernel<<<eGrid, b256, 0, stream>>>(eidx, ideg, E_);
    alloc_kernel<<<nGrid, b256, 0, stream>>>(ideg, istart, icursor, counter, n);
    scatter_kernel<<<eGrid, b256, 0, stream>>>(eidx, icursor, edata, E_);
    // aggregate into ag
    aggr_kernel<<<n4Grid, b256, 0, stream>>>(Vb, attnW, istart, ideg, edata, ag, n);
    // Wo + residual + fused LN2: x2 -> d_out (fp32), h2 (bf16, overlays r2)
    gemm_lds<false, false, true, 1><<<dim3(rb, 1), b256, 0, stream>>>(
        ag, 128, Wt + 49152, 128, bo, out, 128, 0, x, 128, n, g2, be2, h2);
    // fused FFN: relu(h2 @ W1 + b1) @ W2 + b2 + out -> out
    // (replaces FFN1+FFN2; eliminates 205 MB u[N,512] HBM round-trip)
    ffn_fused<<<dim3(rb), b256, 0, stream>>>(
        h2, Wt + 65536, Wt + 131072, b1, b2, out, out, n);
}

// Round 2
// 481.443 us; speedup vs baseline: 1.2255x; 1.2255x over previous
//
#include <hip/hip_runtime.h>
#include <hip/hip_bf16.h>

#define C_DIM 128
#define EPS_LN 1e-5f

typedef short bf16x8 __attribute__((ext_vector_type(8)));
typedef float f32x4  __attribute__((ext_vector_type(4)));
typedef __hip_bfloat16 bf16;

__device__ inline unsigned short f2bu(float f) {
    bf16 h = __float2bfloat16(f);
    return *reinterpret_cast<unsigned short*>(&h);
}
__device__ inline float blo(unsigned int u) { return __uint_as_float(u << 16); }
__device__ inline float bhi(unsigned int u) { return __uint_as_float(u & 0xffff0000u); }
__device__ inline ushort4 pack4(float a, float b, float c, float d) {
    ushort4 r; r.x = f2bu(a); r.y = f2bu(b); r.z = f2bu(c); r.w = f2bu(d); return r;
}

// async global->LDS DMA, 16B per lane. LDS dest is WAVE-UNIFORM base;
// HW writes lane l's 16B at base + l*16. Global src is per-lane.
__device__ inline void async_copy16(const bf16* g, bf16* s) {
    __builtin_amdgcn_global_load_lds(
        (const __attribute__((address_space(1))) unsigned int*)g,
        (__attribute__((address_space(3))) unsigned int*)s,
        16, 0, 0);
}

// ---------------- weights convert+transpose + bias pack, ONE dispatch ------
// dst (bf16): Wqt|Wkt|Wvt|Wot (4x 128*128) | Wt1[512][128] | Wt2[128][512]
// then packed fp32 bqkv[384] right after.
__global__ __launch_bounds__(256) void wconv_all(
    const float* __restrict__ Wq, const float* __restrict__ Wk,
    const float* __restrict__ Wv, const float* __restrict__ Wo,
    const float* __restrict__ W1, const float* __restrict__ W2,
    const float* __restrict__ bq, const float* __restrict__ bk,
    const float* __restrict__ bv, bf16* __restrict__ dst) {
    int idx = blockIdx.x * 256 + threadIdx.x;
    if (idx < 65536) {                       // four 128x128 weights
        int r = idx >> 14, o = idx & 16383;
        int k = o >> 7, nn = o & 127;
        const float* W = (r == 0) ? Wq : (r == 1) ? Wk : (r == 2) ? Wv : Wo;
        dst[(r << 14) + nn * 128 + k] = __float2bfloat16(W[o]);
    } else if (idx < 131072) {               // W1 [128,512] -> Wt1[n][k]
        int o = idx - 65536;
        int k = o >> 9, nn = o & 511;
        dst[65536 + nn * 128 + k] = __float2bfloat16(W1[o]);
    } else if (idx < 196608) {               // W2 [512,128] -> Wt2[n][k]
        int o = idx - 131072;
        int k = o >> 7, nn = o & 127;
        dst[131072 + nn * 512 + k] = __float2bfloat16(W2[o]);
    } else if (idx < 196992) {               // packed bqkv[384] fp32
        int j = idx - 196608;
        int grp = j >> 7, col = j & 127;
        const float* bp = (grp == 0) ? bq : (grp == 1) ? bk : bv;
        ((float*)(dst + 196608))[j] = bp[col];
    }
}

__global__ __launch_bounds__(256) void zeroi_kernel(int* __restrict__ p, int n) {
    int i = blockIdx.x * 256 + threadIdx.x;
    if (i < n) p[i] = 0;
}

// ---------------- LayerNorm fp32 -> bf16, one wave per row -----------------
__global__ __launch_bounds__(256) void ln_kernel(
    const float* __restrict__ x, const float* __restrict__ g,
    const float* __restrict__ b, bf16* __restrict__ out, int n) {
    int wave = threadIdx.x >> 6;
    int lane = threadIdx.x & 63;
    int row = blockIdx.x * 4 + wave;
    if (row >= n) return;
    float2 v = ((const float2*)(x + (size_t)row * C_DIM))[lane];
    float s  = v.x + v.y;
    float ss = v.x * v.x + v.y * v.y;
    #pragma unroll
    for (int o = 1; o < 64; o <<= 1) {
        s  += __shfl_xor(s, o);
        ss += __shfl_xor(ss, o);
    }
    float mu  = s * (1.0f / C_DIM);
    float var = ss * (1.0f / C_DIM) - mu * mu;
    float rs  = rsqrtf(var + EPS_LN);
    float2 gg = ((const float2*)g)[lane];
    float2 bb = ((const float2*)b)[lane];
    __hip_bfloat162 o2;
    o2.x = __float2bfloat16((v.x - mu) * rs * gg.x + bb.x);
    o2.y = __float2bfloat16((v.y - mu) * rs * gg.y + bb.y);
    ((__hip_bfloat162*)(out + (size_t)row * C_DIM))[lane] = o2;
}

// ---------------- LDS-staged MFMA GEMM (global_load_lds + XOR swizzle) -----
// Block: 128 rows x 128 cols of C; 4 waves, each 32 rows x 128 cols.
// A [M,lda] bf16 row-major; Bt [Ncols][Kfull] bf16 (row = output col).
// Staging: async_copy16, wave-uniform LDS base (linear [128][128]), per-lane
// global src pre-swizzled: LDS slot s of row r holds global slot s^(r&7).
// Reads use ((ks*4+q)^(m&7))<<3 -> bank-uniform (2 lanes/bank, free).
// Tail: clamp source row to M-1 (garbage lands only in C rows >= M, masked).
// Operand-swapped mfma(bf, af, acc): lane(m,q) reg r = C[row0+..+m][ct*16+q*4+r].
template<bool OUTBF16, bool RELU, bool FUSE_LN, int KSTEPS>
__global__ __launch_bounds__(256) void gemm_lds(
    const bf16* __restrict__ A, int lda,
    const bf16* __restrict__ Bt, int Kfull,
    const float* __restrict__ biasBase,
    void* __restrict__ Cd, int ldc, size_t obStride,
    const float* __restrict__ resid, int ldres,
    int M,
    const float* __restrict__ g, const float* __restrict__ be,
    bf16* __restrict__ h2) {
    __shared__ bf16 As[128][128];
    __shared__ bf16 Bs[128][128];
    int tid  = threadIdx.x;
    int lane = tid & 63;
    int w    = tid >> 6;
    int m = lane & 15, q = lane >> 4;
    int row0 = blockIdx.x * 128;
    const bf16* Bbase = Bt + (size_t)blockIdx.y * 128 * Kfull;

    f32x4 acc[2][8];
    #pragma unroll
    for (int rt = 0; rt < 2; rt++)
        #pragma unroll
        for (int ct = 0; ct < 8; ct++) acc[rt][ct] = (f32x4){0.f, 0.f, 0.f, 0.f};

    int rsub  = lane >> 4;      // 0..3: this lane's dest row within a 4-row DMA call
    int cslot = lane & 15;      // this lane's 16B slot within the row

    for (int kt = 0; kt < KSTEPS; kt++) {
        // stage A+B tiles [128][128] via 8+8 async DMA calls per wave
        #pragma unroll
        for (int i = 0; i < 8; i++) {
            int arow = w * 32 + i * 4 + rsub;                 // dest row 0..127
            int scol = (cslot ^ (arow & 7)) << 3;             // swizzled src slot (elems)
            int garow = row0 + arow;
            if (garow > M - 1) garow = M - 1;                 // tail clamp
            async_copy16(A + (size_t)garow * lda + kt * 128 + scol, &As[w * 32 + i * 4][0]);
            async_copy16(Bbase + (size_t)arow * Kfull + kt * 128 + scol, &Bs[w * 32 + i * 4][0]);
        }
        __syncthreads();
        #pragma unroll
        for (int ks = 0; ks < 4; ks++) {
            int sofs = ((ks * 4 + q) ^ (m & 7)) << 3;         // swizzled read offset
            bf16x8 af0 = *(const bf16x8*)&As[w * 32 + m][sofs];
            bf16x8 af1 = *(const bf16x8*)&As[w * 32 + 16 + m][sofs];
            #pragma unroll
            for (int ct = 0; ct < 8; ct++) {
                bf16x8 bf = *(const bf16x8*)&Bs[ct * 16 + m][sofs];
                acc[0][ct] = __builtin_amdgcn_mfma_f32_16x16x32_bf16(bf, af0, acc[0][ct], 0, 0, 0);
                acc[1][ct] = __builtin_amdgcn_mfma_f32_16x16x32_bf16(bf, af1, acc[1][ct], 0, 0, 0);
            }
        }
        if (kt + 1 < KSTEPS) __syncthreads();
    }

    // ---- epilogue ----
    #pragma unroll
    for (int rt = 0; rt < 2; rt++) {
        int row = row0 + w * 32 + rt * 16 + m;
        bool valid = row < M;
        float vals[8][4];
        #pragma unroll
        for (int ct = 0; ct < 8; ct++) {
            int col = ct * 16 + q * 4;
            float4 bv = make_float4(0.f, 0.f, 0.f, 0.f);
            if (biasBase) bv = *(const float4*)(biasBase + blockIdx.y * 128 + col);
            float4 rv = make_float4(0.f, 0.f, 0.f, 0.f);
            if (resid && valid) rv = *(const float4*)(resid + (size_t)row * ldres + col);
            vals[ct][0] = acc[rt][ct][0] + bv.x + rv.x;
            vals[ct][1] = acc[rt][ct][1] + bv.y + rv.y;
            vals[ct][2] = acc[rt][ct][2] + bv.z + rv.z;
            vals[ct][3] = acc[rt][ct][3] + bv.w + rv.w;
        }
        if (FUSE_LN) {
            // row spans lanes {m, m+16, m+32, m+48}: reduce over q via xor 16,32
            float s1 = 0.f, s2 = 0.f;
            #pragma unroll
            for (int ct = 0; ct < 8; ct++)
                #pragma unroll
                for (int r = 0; r < 4; r++) { s1 += vals[ct][r]; s2 += vals[ct][r] * vals[ct][r]; }
            s1 += __shfl_xor(s1, 16); s1 += __shfl_xor(s1, 32);
            s2 += __shfl_xor(s2, 16); s2 += __shfl_xor(s2, 32);
            float mu  = s1 * (1.0f / 128.f);
            float var = s2 * (1.0f / 128.f) - mu * mu;
            float rs  = rsqrtf(var + EPS_LN);
            if (valid) {
                #pragma unroll
                for (int ct = 0; ct < 8; ct++) {
                    int col = ct * 16 + q * 4;
                    *(float4*)((float*)Cd + (size_t)row * ldc + col) =
                        make_float4(vals[ct][0], vals[ct][1], vals[ct][2], vals[ct][3]);
                    float4 gg = *(const float4*)(g + col);
                    float4 bb = *(const float4*)(be + col);
                    *(ushort4*)(h2 + (size_t)row * 128 + col) =
                        pack4((vals[ct][0] - mu) * rs * gg.x + bb.x,
                              (vals[ct][1] - mu) * rs * gg.y + bb.y,
                              (vals[ct][2] - mu) * rs * gg.z + bb.z,
                              (vals[ct][3] - mu) * rs * gg.w + bb.w);
                }
            }
        } else if (valid) {
            #pragma unroll
            for (int ct = 0; ct < 8; ct++) {
                int col = ct * 16 + q * 4;
                float v0 = vals[ct][0], v1 = vals[ct][1];
                float v2 = vals[ct][2], v3 = vals[ct][3];
                if (RELU) {
                    v0 = fmaxf(v0, 0.f); v1 = fmaxf(v1, 0.f);
                    v2 = fmaxf(v2, 0.f); v3 = fmaxf(v3, 0.f);
                }
                if (OUTBF16) {
                    *(ushort4*)((bf16*)Cd + blockIdx.y * obStride + (size_t)row * ldc + col) =
                        pack4(v0, v1, v2, v3);
                } else {
                    *(float4*)((float*)Cd + blockIdx.y * obStride + (size_t)row * ldc + col) =
                        make_float4(v0, v1, v2, v3);
                }
            }
        }
    }
}

// ---------------- attention: 8 edges/wave, one head per lane ---------------
__device__ inline float dot8(uint4 a, uint4 b) {
    return blo(a.x) * blo(b.x) + bhi(a.x) * bhi(b.x)
         + blo(a.y) * blo(b.y) + bhi(a.y) * bhi(b.y)
         + blo(a.z) * blo(b.z) + bhi(a.z) * bhi(b.z)
         + blo(a.w) * blo(b.w) + bhi(a.w) * bhi(b.w);
}

__global__ __launch_bounds__(256) void attn_kernel(
    const bf16* __restrict__ Q, const bf16* __restrict__ K,
    const int* __restrict__ eidx, float* __restrict__ attn, int E_) {
    int gw = blockIdx.x * 4 + (threadIdx.x >> 6);
    int lane = threadIdx.x & 63;
    int e = gw * 8 + (lane >> 3);
    int h = lane & 7;
    bool v = e < E_;
    int src = v ? eidx[e] : 0;
    int dst = v ? eidx[E_ + e] : 0;
    const uint4* qp = (const uint4*)(Q + (size_t)dst * 128 + h * 16);
    const uint4* kp = (const uint4*)(K + (size_t)src * 128 + h * 16);
    uint4 q0 = qp[0], q1 = qp[1];
    uint4 k0 = kp[0], k1 = kp[1];
    float s = (dot8(q0, k0) + dot8(q1, k1)) * 0.25f;   // / sqrt(16)
    float mx = s;
    mx = fmaxf(mx, __shfl_xor(mx, 1));
    mx = fmaxf(mx, __shfl_xor(mx, 2));
    mx = fmaxf(mx, __shfl_xor(mx, 4));
    float ex = expf(s - mx);
    float sum = ex;
    sum += __shfl_xor(sum, 1);
    sum += __shfl_xor(sum, 2);
    sum += __shfl_xor(sum, 4);
    if (v) attn[(size_t)e * 8 + h] = ex / sum;   // coalesced: gw*64+lane
}

// ---------------- CSR build ------------------------------------------------
__global__ __launch_bounds__(256) void hist_kernel(
    const int* __restrict__ eidx, int* __restrict__ deg, int E_) {
    int e = blockIdx.x * 256 + threadIdx.x;
    if (e >= E_) return;
    atomicAdd(&deg[eidx[E_ + e]], 1);
}

__global__ __launch_bounds__(256) void alloc_kernel(
    const int* __restrict__ deg, int* __restrict__ start,
    int* __restrict__ cursor, int* __restrict__ counter, int n) {
    int i = blockIdx.x * 256 + threadIdx.x;
    if (i >= n) return;
    int d = deg[i];
    int s = atomicAdd(counter, d);
    start[i] = s;
    cursor[i] = s;
}

__global__ __launch_bounds__(256) void scatter_kernel(
    const int* __restrict__ eidx, int* __restrict__ cursor,
    int2* __restrict__ edata, int E_) {
    int e = blockIdx.x * 256 + threadIdx.x;
    if (e >= E_) return;
    int src = eidx[e];
    int dst = eidx[E_ + e];
    int pos = atomicAdd(&cursor[dst], 1);
    edata[pos] = make_int2(src, e);
}

// ---------------- aggregation: one wave/node, 2-way unrolled ---------------
__global__ __launch_bounds__(256) void aggr_kernel(
    const bf16* __restrict__ V, const float* __restrict__ attnW,
    const int* __restrict__ start, const int* __restrict__ deg,
    const int2* __restrict__ edata, bf16* __restrict__ ag, int n) {
    int wave = threadIdx.x >> 6;
    int lane = threadIdx.x & 63;
    int i = blockIdx.x * 4 + wave;
    if (i >= n) return;
    int s = start[i], d = deg[i];
    int h = lane >> 3;
    float ax = 0.f, ay = 0.f, bx = 0.f, by = 0.f;
    int j = s, e_ = s + d;
    for (; j + 2 <= e_; j += 2) {
        int2 e0 = edata[j], e1 = edata[j + 1];
        float a0 = attnW[(size_t)e0.y * 8 + h];
        float a1 = attnW[(size_t)e1.y * 8 + h];
        unsigned u0 = ((const unsigned*)(V + (size_t)e0.x * 128))[lane];
        unsigned u1 = ((const unsigned*)(V + (size_t)e1.x * 128))[lane];
        ax += a0 * blo(u0); ay += a0 * bhi(u0);
        bx += a1 * blo(u1); by += a1 * bhi(u1);
    }
    if (j < e_) {
        int2 e0 = edata[j];
        float a0 = attnW[(size_t)e0.y * 8 + h];
        unsigned u0 = ((const unsigned*)(V + (size_t)e0.x * 128))[lane];
        ax += a0 * blo(u0); ay += a0 * bhi(u0);
    }
    ax += bx; ay += by;
    __hip_bfloat162 o2;
    o2.x = __float2bfloat16(ax);
    o2.y = __float2bfloat16(ay);
    ((__hip_bfloat162*)(ag + (size_t)i * 128))[lane] = o2;
}

extern "C" void kernel_launch(void* const* d_in, const int* in_sizes, int n_in,
                              void* d_out, int out_size, void* d_ws, size_t ws_size,
                              hipStream_t stream) {
    const float* x   = (const float*)d_in[0];
    const int*  eidx = (const int*)d_in[1];
    const float* Wq = (const float*)d_in[2];  const float* bq = (const float*)d_in[3];
    const float* Wk = (const float*)d_in[4];  const float* bk = (const float*)d_in[5];
    const float* Wv = (const float*)d_in[6];  const float* bv = (const float*)d_in[7];
    const float* Wo = (const float*)d_in[8];  const float* bo = (const float*)d_in[9];
    const float* W1 = (const float*)d_in[10]; const float* b1 = (const float*)d_in[11];
    const float* W2 = (const float*)d_in[12]; const float* b2 = (const float*)d_in[13];
    const float* g1 = (const float*)d_in[14]; const float* be1 = (const float*)d_in[15];
    const float* g2 = (const float*)d_in[16]; const float* be2 = (const float*)d_in[17];
    float* out = (float*)d_out;

    int n  = in_sizes[0] / C_DIM;   // 100000
    int E_ = in_sizes[1] / 2;       // 600000
    size_t nf = (size_t)n * 128;

    // ---- workspace (~154 MB) ----
    bf16* Wt    = (bf16*)d_ws;                // 196608 bf16 transposed weights
    float* bqkv = (float*)(Wt + 196608);      // packed [bq|bk|bv]
    bf16* reg0  = (bf16*)(bqkv + 384);        // 4*nf: h1|Q|K|V ; u overlays all
    bf16* h1 = reg0;
    bf16* Qb = reg0 + nf;
    bf16* Kb = reg0 + 2 * nf;
    bf16* Vb = reg0 + 3 * nf;
    bf16* uB = reg0;                          // [N,512] bf16 (FFN intermediate)
    bf16* ag = reg0 + 4 * nf;                 // [N,128]
    char* r2 = (char*)(ag + nf);              // union region
    float* attnW = (float*)r2;                // [E,8] fp32
    int2* edata  = (int2*)(attnW + (size_t)E_ * 8);
    int*  ideg   = (int*)(edata + E_);
    int*  counter = ideg + n;
    int*  istart  = ideg + n + 1;
    int*  icursor = istart + n;
    bf16* h2 = (bf16*)r2;                     // overlays attnW/edata/CSR after aggr

    dim3 b256(256);
    dim3 lnGrid((n + 3) / 4);
    int rb = (n + 127) / 128;                 // 782
    dim3 eGrid8((E_ + 31) / 32);
    dim3 eGrid((E_ + 255) / 256);
    dim3 nGrid((n + 255) / 256);
    dim3 n1Grid((n + 1 + 255) / 256);
    dim3 n4Grid((n + 3) / 4);

    // weights -> bf16 transposed + packed bqkv (one dispatch)
    wconv_all<<<dim3(770), b256, 0, stream>>>(Wq, Wk, Wv, Wo, W1, W2, bq, bk, bv, Wt);
    // zero deg+counter
    zeroi_kernel<<<n1Grid, b256, 0, stream>>>(ideg, n + 1);
    // LN1: x -> h1
    ln_kernel<<<lnGrid, b256, 0, stream>>>(x, g1, be1, h1, n);
    // QKV: one dispatch, col-blocks -> Q|K|V buffers (obStride = nf)
    gemm_lds<true, false, false, 1><<<dim3(rb, 3), b256, 0, stream>>>(
        h1, 128, Wt, 128, bqkv, Qb, 128, nf, nullptr, 0, n, nullptr, nullptr, nullptr);
    // attention weights
    attn_kernel<<<eGrid8, b256, 0, stream>>>(Qb, Kb, eidx, attnW, E_);
    // CSR build
    hist_kernel<<<eGrid, b256, 0, stream>>>(eidx, ideg, E_);
    alloc_kernel<<<nGrid, b256, 0, stream>>>(ideg, istart, icursor, counter, n);
    scatter_kernel<<<eGrid, b256, 0, stream>>>(eidx, icursor, edata, E_);
    // aggregate into ag
    aggr_kernel<<<n4Grid, b256, 0, stream>>>(Vb, attnW, istart, ideg, edata, ag, n);
    // Wo + residual + fused LN2: x2 -> d_out (fp32), h2 (bf16, overlays r2)
    gemm_lds<false, false, true, 1><<<dim3(rb, 1), b256, 0, stream>>>(
        ag, 128, Wt + 49152, 128, bo, out, 128, 0, x, 128, n, g2, be2, h2);
    // FFN1: h2 @ W1 + b1, ReLU -> u [N,512] bf16 (overlays h1|Q|K|V, all dead)
    gemm_lds<true, true, false, 1><<<dim3(rb, 4), b256, 0, stream>>>(
        h2, 128, Wt + 65536, 128, b1, uB, 512, 128, nullptr, 0, n, nullptr, nullptr, nullptr);
    // FFN2: u @ W2 + b2 + x2 -> d_out (K=512 -> 4 k-tiles)
    gemm_lds<false, false, false, 4><<<dim3(rb, 1), b256, 0, stream>>>(
        uB, 512, Wt + 131072, 512, b2, out, 128, 0, out, 128, n, nullptr, nullptr, nullptr);
}